// Round 4
// baseline (1006.079 us; speedup 1.0000x reference)
//
#include <hip/hip_runtime.h>

#define TOKS   32768
#define NEXP   64
#define DDIM   1024
#define SEQ    8192
#define NBATCH 4
#define TPB    64      // tokens per block
#define LSTR   68      // epilogue row stride (16B-aligned rows)
#define CSTR   21      // candidate row stride (odd -> 2-way max across lanes)

// ---------------- main kernel: fp32 GEMM + softmax + top-9 + flagging ----------------
// LDS tiles are stored SWIZZLED: physical col p = (c + (row & 60)) & 63.
// This makes the transposed b128 staging stores bank-optimal (8 phases) --
// padding alone cannot (any 16B-aligned stride collapses to 2 bank groups).
__global__ __launch_bounds__(256, 2) void moe_gate_main(
    const float* __restrict__ X, const float* __restrict__ W,
    float* __restrict__ out, float* __restrict__ gsum, float* __restrict__ gce,
    int* __restrict__ flag_cnt, int* __restrict__ flag_tok)
{
  __shared__ __align__(16) float smem[16384];  // 64 KB: xb0|xb1|wb0|wb1 (4096 each)
  __shared__ float red[256];
  __shared__ float gmx[64];
  __shared__ float cval[64 * CSTR];
  __shared__ int   cidx[64 * CSTR];
  __shared__ int   hist[NEXP];

  float* const xb0 = smem;
  float* const xb1 = smem + 4096;
  float* const wb0 = smem + 8192;
  float* const wb1 = smem + 12288;

  const int tid = threadIdx.x;
  const int tok_base = blockIdx.x * TPB;
  const int bb = blockIdx.x >> 7;        // 128 blocks per batch

  // staging mapping
  const int lc = tid & 15;               // d-quad
  const int lr = tid >> 4;               // row-quad (tokens / expert rows 4*lr+i)
  // compute mapping: wave q owns d-slice [q*16, q*16+16) of each 64-d tile
  const int l  = tid & 63;
  const int q  = tid >> 6;
  const int t0c = (l >> 3) * 8;          // 8 tokens
  const int e0c = (l & 7) * 8;           // 8 experts
  const int dq = q * 16;
  const int pcol = (4 * lr + 4 * lc) & 63;   // swizzled store col (rows 4lc+j: rot=4lc)

  float acc[8][8];
#pragma unroll
  for (int i = 0; i < 8; ++i)
#pragma unroll
    for (int j = 0; j < 8; ++j) acc[i][j] = 0.0f;

  float4 px[4], pw[4];
#pragma unroll
  for (int i = 0; i < 4; ++i) {
    px[i] = *(const float4*)(X + (size_t)(tok_base + 4 * lr + i) * DDIM + 4 * lc);
    pw[i] = *(const float4*)(W + (size_t)(4 * lr + i) * DDIM + 4 * lc);
  }
  // stage tile 0
#pragma unroll
  for (int j = 0; j < 4; ++j) {
    float4 vx = make_float4(((const float*)&px[0])[j], ((const float*)&px[1])[j],
                            ((const float*)&px[2])[j], ((const float*)&px[3])[j]);
    float4 vw = make_float4(((const float*)&pw[0])[j], ((const float*)&pw[1])[j],
                            ((const float*)&pw[2])[j], ((const float*)&pw[3])[j]);
    *(float4*)&xb0[(4 * lc + j) * 64 + pcol] = vx;
    *(float4*)&wb0[(4 * lc + j) * 64 + pcol] = vw;
  }
  __syncthreads();

#pragma unroll 2
  for (int kt = 0; kt < 16; ++kt) {
    float* const xbc = (kt & 1) ? xb1 : xb0;
    float* const wbc = (kt & 1) ? wb1 : wb0;
    float* const xbn = (kt & 1) ? xb0 : xb1;
    float* const wbn = (kt & 1) ? wb0 : wb1;

    if (kt < 15) {
      const int dbase = (kt + 1) * 64;
#pragma unroll
      for (int i = 0; i < 4; ++i) {
        px[i] = *(const float4*)(X + (size_t)(tok_base + 4 * lr + i) * DDIM + dbase + 4 * lc);
        pw[i] = *(const float4*)(W + (size_t)(4 * lr + i) * DDIM + dbase + 4 * lc);
      }
    }
    // compute on current buffer (reads are broadcast/2-way: conflict-free)
#pragma unroll
    for (int d = 0; d < 16; ++d) {
      const int row = dq + d;
      const int rot = dq + (d & 12);       // == row & 60 (dq % 16 == 0)
      const float* xr = xbc + row * 64;
      const float* wr = wbc + row * 64;
      float xv[8], wv[8];
      *(float4*)&xv[0] = *(const float4*)(xr + ((t0c + rot) & 63));
      *(float4*)&xv[4] = *(const float4*)(xr + ((t0c + 4 + rot) & 63));
      *(float4*)&wv[0] = *(const float4*)(wr + ((e0c + rot) & 63));
      *(float4*)&wv[4] = *(const float4*)(wr + ((e0c + 4 + rot) & 63));
#pragma unroll
      for (int i = 0; i < 8; ++i)
#pragma unroll
        for (int j = 0; j < 8; ++j)
          acc[i][j] = fmaf(xv[i], wv[j], acc[i][j]);
    }
    // stage next tile into the other buffer (no race: nobody reads it this kt)
    if (kt < 15) {
#pragma unroll
      for (int j = 0; j < 4; ++j) {
        float4 vx = make_float4(((const float*)&px[0])[j], ((const float*)&px[1])[j],
                                ((const float*)&px[2])[j], ((const float*)&px[3])[j]);
        float4 vw = make_float4(((const float*)&pw[0])[j], ((const float*)&pw[1])[j],
                                ((const float*)&pw[2])[j], ((const float*)&pw[3])[j]);
        *(float4*)&xbn[(4 * lc + j) * 64 + pcol] = vx;
        *(float4*)&wbn[(4 * lc + j) * 64 + pcol] = vw;
      }
    }
    __syncthreads();
  }

  // ---- split-K combine: logits = ((q0+q2) + (q1+q3)), final in wave 0 ----
  float* const bufA = smem;          // scratch A (later: logitsT)
  float* const bufB = smem + 4352;   // scratch B (later: scoresT)
  float* const LOG  = smem + 8704;   // row-major logits [t][LSTR]
  float* const LOGT = smem;          // transposed logits [e][LSTR]
  float* const scoT = smem + 4352;   // transposed scores [e][LSTR]

  if (q == 2) {
#pragma unroll
    for (int i = 0; i < 8; ++i) {
      *(float4*)&bufA[(t0c + i) * LSTR + e0c]     = *(float4*)&acc[i][0];
      *(float4*)&bufA[(t0c + i) * LSTR + e0c + 4] = *(float4*)&acc[i][4];
    }
  }
  if (q == 3) {
#pragma unroll
    for (int i = 0; i < 8; ++i) {
      *(float4*)&bufB[(t0c + i) * LSTR + e0c]     = *(float4*)&acc[i][0];
      *(float4*)&bufB[(t0c + i) * LSTR + e0c + 4] = *(float4*)&acc[i][4];
    }
  }
  __syncthreads();
  if (q == 0) {
#pragma unroll
    for (int i = 0; i < 8; ++i) {
      float4 a = *(const float4*)&bufA[(t0c + i) * LSTR + e0c];
      float4 b = *(const float4*)&bufA[(t0c + i) * LSTR + e0c + 4];
      acc[i][0] += a.x; acc[i][1] += a.y; acc[i][2] += a.z; acc[i][3] += a.w;
      acc[i][4] += b.x; acc[i][5] += b.y; acc[i][6] += b.z; acc[i][7] += b.w;
    }
  }
  if (q == 1) {
#pragma unroll
    for (int i = 0; i < 8; ++i) {
      float4 a = *(const float4*)&bufB[(t0c + i) * LSTR + e0c];
      float4 b = *(const float4*)&bufB[(t0c + i) * LSTR + e0c + 4];
      acc[i][0] += a.x; acc[i][1] += a.y; acc[i][2] += a.z; acc[i][3] += a.w;
      acc[i][4] += b.x; acc[i][5] += b.y; acc[i][6] += b.z; acc[i][7] += b.w;
    }
  }
  __syncthreads();
  if (q == 1) {
#pragma unroll
    for (int i = 0; i < 8; ++i) {
      *(float4*)&bufA[(t0c + i) * LSTR + e0c]     = *(float4*)&acc[i][0];
      *(float4*)&bufA[(t0c + i) * LSTR + e0c + 4] = *(float4*)&acc[i][4];
    }
  }
  __syncthreads();
  if (q == 0) {
    // reads of bufA complete (program order, may-alias) before LOGT writes below
#pragma unroll
    for (int i = 0; i < 8; ++i) {
      float4 a = *(const float4*)&bufA[(t0c + i) * LSTR + e0c];
      float4 b = *(const float4*)&bufA[(t0c + i) * LSTR + e0c + 4];
      acc[i][0] += a.x; acc[i][1] += a.y; acc[i][2] += a.z; acc[i][3] += a.w;
      acc[i][4] += b.x; acc[i][5] += b.y; acc[i][6] += b.z; acc[i][7] += b.w;
    }
#pragma unroll
    for (int i = 0; i < 8; ++i) {
      *(float4*)&LOG[(t0c + i) * LSTR + e0c]     = *(float4*)&acc[i][0];
      *(float4*)&LOG[(t0c + i) * LSTR + e0c + 4] = *(float4*)&acc[i][4];
    }
#pragma unroll
    for (int j = 0; j < 8; ++j) {
      *(float4*)&LOGT[(e0c + j) * LSTR + t0c] =
          make_float4(acc[0][j], acc[1][j], acc[2][j], acc[3][j]);
      *(float4*)&LOGT[(e0c + j) * LSTR + t0c + 4] =
          make_float4(acc[4][j], acc[5][j], acc[6][j], acc[7][j]);
    }
    hist[l] = 0;
  }
  __syncthreads();

  // ---- softmax over 64 experts (lane=token reads of LOGT: conflict-free) ----
  const int t = l;
  float m = -__builtin_huge_valf();
#pragma unroll
  for (int e = 0; e < 16; ++e) m = fmaxf(m, LOGT[(dq + e) * LSTR + t]);
  red[q * 64 + t] = m;
  __syncthreads();
  float gm = fmaxf(fmaxf(red[t], red[64 + t]), fmaxf(red[128 + t], red[192 + t]));
  if (q == 0) gmx[t] = gm;
  float z = 0.0f;
#pragma unroll
  for (int e = 0; e < 16; ++e) {
    float ev = expf(LOGT[(dq + e) * LSTR + t] - gm);
    scoT[(dq + e) * LSTR + t] = ev;
    z += ev;
  }
  __syncthreads();
  red[q * 64 + t] = z;
  __syncthreads();
  float Z = red[t] + red[64 + t] + red[128 + t] + red[192 + t];
  float invZ = 1.0f / Z;
#pragma unroll
  for (int e = 0; e < 16; ++e) scoT[(dq + e) * LSTR + t] *= invZ;
  __syncthreads();

  // aux partials: per-expert sums over this block's tokens (vectorized, optimal banks)
  {
    const int e = l, g = q;
    float4 s0 = *(const float4*)&scoT[e * LSTR + g * 16];
    float4 s1 = *(const float4*)&scoT[e * LSTR + g * 16 + 4];
    float4 s2 = *(const float4*)&scoT[e * LSTR + g * 16 + 8];
    float4 s3 = *(const float4*)&scoT[e * LSTR + g * 16 + 12];
    red[g * 64 + e] = ((s0.x + s0.y) + (s0.z + s0.w)) + ((s1.x + s1.y) + (s1.z + s1.w)) +
                      ((s2.x + s2.y) + (s2.z + s2.w)) + ((s3.x + s3.y) + (s3.z + s3.w));
  }
  __syncthreads();
  if (tid < 64) {
    float tot = red[tid] + red[64 + tid] + red[128 + tid] + red[192 + tid];
    atomicAdd(&gsum[bb * 64 + tid], tot);
  }

  // top-9 phase 1: per half (32 experts), strict > + ascending scan == jax tie-break
  if (tid < 128) {
    const int h = tid >> 6;
    const int eb = h * 32;
#pragma unroll 1
    for (int k = 0; k < 9; ++k) {
      float mv = -1.0f; int mi = eb;
#pragma unroll 4
      for (int e = 0; e < 32; ++e) {
        float v = scoT[(eb + e) * LSTR + t];
        if (v > mv) { mv = v; mi = eb + e; }
      }
      cval[t * CSTR + h * 9 + k] = mv;
      cidx[t * CSTR + h * 9 + k] = mi;
      scoT[mi * LSTR + t] = -1.0f;
    }
  }
  __syncthreads();

  // merge 18 -> top-9; flag near-ties for f64 refinement
  if (tid < 64) {
    float wv[9]; int wi[8];
#pragma unroll 1
    for (int k = 0; k < 9; ++k) {
      float mv = -1.0f; int mj = 0;
#pragma unroll 3
      for (int j = 0; j < 18; ++j) {
        float v = cval[t * CSTR + j];
        if (v > mv) { mv = v; mj = j; }
      }
      wv[k] = mv;
      if (k < 8) {
        wi[k] = cidx[t * CSTR + mj];
        atomicAdd(&hist[wi[k]], 1);
      }
      cval[t * CSTR + mj] = -1.0f;
    }
    bool flag = false;
#pragma unroll
    for (int k = 0; k < 8; ++k)
      if (wv[k + 1] >= wv[k] * (1.0f - 2.0e-5f)) flag = true;
    if (flag) {
      int p = atomicAdd(flag_cnt, 1);
      flag_tok[p] = tok_base + t;
    }
    // weights from f64 exp of logits (Z cancels in renorm; eps 1e-20 negligible)
    double ed[8]; double den = 0.0;
#pragma unroll
    for (int k = 0; k < 8; ++k) {
      ed[k] = exp((double)LOG[t * LSTR + wi[k]] - (double)gmx[t]);
      den += ed[k];
    }
    const size_t tg = (size_t)(tok_base + t);
    *(float4*)(out + tg * 8) =
        make_float4((float)wi[0], (float)wi[1], (float)wi[2], (float)wi[3]);
    *(float4*)(out + tg * 8 + 4) =
        make_float4((float)wi[4], (float)wi[5], (float)wi[6], (float)wi[7]);
    *(float4*)(out + (size_t)TOKS * 8 + tg * 8) =
        make_float4((float)(ed[0] / den), (float)(ed[1] / den),
                    (float)(ed[2] / den), (float)(ed[3] / den));
    *(float4*)(out + (size_t)TOKS * 8 + tg * 8 + 4) =
        make_float4((float)(ed[4] / den), (float)(ed[5] / den),
                    (float)(ed[6] / den), (float)(ed[7] / den));
  }
  __syncthreads();
  if (tid < 64) atomicAdd(&gce[bb * 64 + tid], (float)hist[tid]);
}

// ---------------- f64 refinement for flagged (near-tie) tokens ----------------
__global__ __launch_bounds__(256) void moe_refine(
    const float* __restrict__ X, const float* __restrict__ W,
    float* __restrict__ out, float* __restrict__ gce,
    const int* __restrict__ flag_cnt, const int* __restrict__ flag_tok)
{
  __shared__ __align__(16) float xrow[DDIM];
  __shared__ double part[4][NEXP];
  const int tid = threadIdx.x;
  const int n = *flag_cnt;
  const int e = tid & 63;
  const int c = tid >> 6;          // K-chunk of 256
#pragma unroll 1
  for (int it = blockIdx.x; it < n; it += 256) {
    const int tok = flag_tok[it];
    __syncthreads();
    *(float4*)&xrow[tid * 4] = *(const float4*)&X[(size_t)tok * DDIM + tid * 4];
    __syncthreads();
    const float* wr = W + (size_t)e * DDIM + c * 256;
    const float* xr = xrow + c * 256;
    double s0 = 0.0, s1 = 0.0, s2 = 0.0, s3 = 0.0;
#pragma unroll 4
    for (int j = 0; j < 256; j += 4) {
      s0 += (double)xr[j]     * (double)wr[j];
      s1 += (double)xr[j + 1] * (double)wr[j + 1];
      s2 += (double)xr[j + 2] * (double)wr[j + 2];
      s3 += (double)xr[j + 3] * (double)wr[j + 3];
    }
    part[c][e] = (s0 + s1) + (s2 + s3);
    __syncthreads();
    if (tid < 64) {
      double cur = (part[0][e] + part[1][e]) + (part[2][e] + part[3][e]);
      int wi[8]; double wl[8];
#pragma unroll 1
      for (int k = 0; k < 8; ++k) {
        double mv = cur; int mi = e;
#pragma unroll
        for (int off = 1; off < 64; off <<= 1) {
          double ov = __shfl_xor(mv, off);
          int    oi = __shfl_xor(mi, off);
          if (ov > mv || (ov == mv && oi < mi)) { mv = ov; mi = oi; }
        }
        wi[k] = mi; wl[k] = mv;
        if (e == mi) cur = -1.0e300;   // knock out winner in its owner lane
      }
      if (e == 0) {
        int olde[8];
#pragma unroll
        for (int k = 0; k < 8; ++k) olde[k] = (int)out[(size_t)tok * 8 + k];
        double ex[8]; double den = 0.0;
#pragma unroll
        for (int k = 0; k < 8; ++k) { ex[k] = exp(wl[k] - wl[0]); den += ex[k]; }
#pragma unroll
        for (int k = 0; k < 8; ++k) {
          out[(size_t)tok * 8 + k] = (float)wi[k];
          out[(size_t)TOKS * 8 + (size_t)tok * 8 + k] = (float)(ex[k] / den);
        }
        const int bbb = tok >> 13;
#pragma unroll 1
        for (int k = 0; k < 8; ++k) {
          bool in_new = false, in_old = false;
          for (int j = 0; j < 8; ++j) {
            if (wi[j] == olde[k]) in_new = true;
            if (olde[j] == wi[k]) in_old = true;
          }
          if (!in_new) atomicAdd(&gce[bbb * 64 + olde[k]], -1.0f);
          if (!in_old) atomicAdd(&gce[bbb * 64 + wi[k]], 1.0f);
        }
      }
    }
  }
}

// ---------------- aux loss reduction ----------------
__global__ void moe_gate_aux(const float* __restrict__ gsum,
                             const float* __restrict__ gce,
                             float* __restrict__ out)
{
  __shared__ float r[256];
  const int tid = threadIdx.x;
  r[tid] = gce[tid] * gsum[tid];
  __syncthreads();
  for (int s = 128; s > 0; s >>= 1) {
    if (tid < s) r[tid] += r[tid + s];
    __syncthreads();
  }
  if (tid == 0)
    out[(size_t)TOKS * 16] = 0.1f * r[0] / ((float)SEQ * (float)NBATCH);
}

extern "C" void kernel_launch(void* const* d_in, const int* in_sizes, int n_in,
                              void* d_out, int out_size, void* d_ws, size_t ws_size,
                              hipStream_t stream)
{
  const float* X = (const float*)d_in[0];   // [4,8192,1024] fp32
  const float* W = (const float*)d_in[1];   // [64,1024] fp32
  float* out  = (float*)d_out;              // idx[T*8] | weights[T*8] | aux
  float* gsum = (float*)d_ws;               // [4][64]
  float* gce  = gsum + NBATCH * NEXP;       // [4][64]
  int* flag_cnt = (int*)((char*)d_ws + 2048);
  int* flag_tok = (int*)((char*)d_ws + 2176);

  hipMemsetAsync(d_ws, 0, 2176, stream);
  moe_gate_main<<<TOKS / TPB, 256, 0, stream>>>(X, W, out, gsum, gce, flag_cnt, flag_tok);
  moe_refine<<<256, 256, 0, stream>>>(X, W, out, gce, flag_cnt, flag_tok);
  moe_gate_aux<<<1, 256, 0, stream>>>(gsum, gce, out);
}

// Round 5
// 242.136 us; speedup vs baseline: 4.1550x; 4.1550x over previous
//
#include <hip/hip_runtime.h>

#define TOKS   32768
#define NEXP   64
#define DDIM   1024
#define SEQ    8192
#define NBATCH 4
#define TPB    64      // tokens per block
#define STR    68      // epilogue row stride (floats)
#define CSTR   21      // candidate row stride (odd -> <=2-way across lanes)

// ---------------- main kernel: fp32 GEMM + softmax + top-9 + flagging ----------------
// Staged tiles use row stride 64 with a bank-rotation swizzle:
//   physical col = (logical col + (row & 60)) & 63
// making the transposed b128 staging stores bank-optimal (8 phases; was ~32).
// Compute-phase reads stay broadcast/2-way (free). Epilogue reuses the same
// LDS at stride 68 (tile phase only touches the first 4096 of 4352 floats).
__global__ __launch_bounds__(256, 2) void moe_gate_main(
    const float* __restrict__ X, const float* __restrict__ W,
    float* __restrict__ out, float* __restrict__ gsum, float* __restrict__ gce,
    int* __restrict__ flag_cnt, int* __restrict__ flag_tok)
{
  __shared__ __align__(16) float xs[64 * STR];   // tile X^T (swizzled) -> scoresT[e][t]
  __shared__ __align__(16) float wsm[64 * STR];  // tile W^T (swizzled) -> logits[t][e]
  __shared__ float red[256];
  __shared__ float gmx[64];
  __shared__ float cval[64 * CSTR];
  __shared__ int   cidx[64 * CSTR];
  __shared__ int   hist[NEXP];

  const int tid = threadIdx.x;
  const int tok_base = blockIdx.x * TPB;
  const int bb = blockIdx.x >> 7;        // 128 blocks per batch

  // staging mapping
  const int lc = tid & 15;               // d-quad
  const int lr = tid >> 4;               // row-quad
  // compute mapping: wave q owns d-slice [q*16, q*16+16) of each 64-d tile
  const int l  = tid & 63;
  const int q  = tid >> 6;
  const int t0c = (l >> 3) * 8;          // 8 tokens
  const int e0c = (l & 7) * 8;           // 8 experts
  const int dq = q * 16;
  const int pcol = (4 * lr + 4 * lc) & 63;   // swizzled store col (rows 4lc+j: rot=4lc)

  float acc[8][8];
#pragma unroll
  for (int i = 0; i < 8; ++i)
#pragma unroll
    for (int j = 0; j < 8; ++j) acc[i][j] = 0.0f;

  float4 px[4], pw[4];
#pragma unroll
  for (int i = 0; i < 4; ++i) {
    px[i] = *(const float4*)(X + (size_t)(tok_base + 4 * lr + i) * DDIM + 4 * lc);
    pw[i] = *(const float4*)(W + (size_t)(4 * lr + i) * DDIM + 4 * lc);
  }

#pragma unroll 1
  for (int kt = 0; kt < DDIM / 64; ++kt) {
    __syncthreads();
#pragma unroll
    for (int j = 0; j < 4; ++j) {
      float4 vx = make_float4(((const float*)&px[0])[j], ((const float*)&px[1])[j],
                              ((const float*)&px[2])[j], ((const float*)&px[3])[j]);
      float4 vw = make_float4(((const float*)&pw[0])[j], ((const float*)&pw[1])[j],
                              ((const float*)&pw[2])[j], ((const float*)&pw[3])[j]);
      *(float4*)&xs[(4 * lc + j) * 64 + pcol] = vx;
      *(float4*)&wsm[(4 * lc + j) * 64 + pcol] = vw;
    }
    __syncthreads();
    if (kt + 1 < DDIM / 64) {
      const int dbase = (kt + 1) * 64;
#pragma unroll
      for (int i = 0; i < 4; ++i) {
        px[i] = *(const float4*)(X + (size_t)(tok_base + 4 * lr + i) * DDIM + dbase + 4 * lc);
        pw[i] = *(const float4*)(W + (size_t)(4 * lr + i) * DDIM + dbase + 4 * lc);
      }
    }
#pragma unroll
    for (int d = 0; d < 16; ++d) {
      const int row = dq + d;
      const int rot = dq + (d & 12);       // == row & 60 (dq % 16 == 0)
      const float* xr = &xs[row * 64];
      const float* wr = &wsm[row * 64];
      float xv[8], wv[8];
      *(float4*)&xv[0] = *(const float4*)(xr + ((t0c + rot) & 63));
      *(float4*)&xv[4] = *(const float4*)(xr + ((t0c + 4 + rot) & 63));
      *(float4*)&wv[0] = *(const float4*)(wr + ((e0c + rot) & 63));
      *(float4*)&wv[4] = *(const float4*)(wr + ((e0c + 4 + rot) & 63));
#pragma unroll
      for (int i = 0; i < 8; ++i)
#pragma unroll
        for (int j = 0; j < 8; ++j)
          acc[i][j] = fmaf(xv[i], wv[j], acc[i][j]);
    }
  }

  // ---- split-K combine: logits = (q0+q2) + (q1+q3), final in wave 0 ----
  __syncthreads();
  if (q == 2) {
#pragma unroll
    for (int i = 0; i < 8; ++i) {
      *(float4*)&xs[(t0c + i) * STR + e0c]     = *(float4*)&acc[i][0];
      *(float4*)&xs[(t0c + i) * STR + e0c + 4] = *(float4*)&acc[i][4];
    }
  }
  if (q == 3) {
#pragma unroll
    for (int i = 0; i < 8; ++i) {
      *(float4*)&wsm[(t0c + i) * STR + e0c]     = *(float4*)&acc[i][0];
      *(float4*)&wsm[(t0c + i) * STR + e0c + 4] = *(float4*)&acc[i][4];
    }
  }
  __syncthreads();
  if (q == 0) {
#pragma unroll
    for (int i = 0; i < 8; ++i) {
      float4 a = *(const float4*)&xs[(t0c + i) * STR + e0c];
      float4 b = *(const float4*)&xs[(t0c + i) * STR + e0c + 4];
      acc[i][0] += a.x; acc[i][1] += a.y; acc[i][2] += a.z; acc[i][3] += a.w;
      acc[i][4] += b.x; acc[i][5] += b.y; acc[i][6] += b.z; acc[i][7] += b.w;
    }
  }
  if (q == 1) {
#pragma unroll
    for (int i = 0; i < 8; ++i) {
      float4 a = *(const float4*)&wsm[(t0c + i) * STR + e0c];
      float4 b = *(const float4*)&wsm[(t0c + i) * STR + e0c + 4];
      acc[i][0] += a.x; acc[i][1] += a.y; acc[i][2] += a.z; acc[i][3] += a.w;
      acc[i][4] += b.x; acc[i][5] += b.y; acc[i][6] += b.z; acc[i][7] += b.w;
    }
  }
  __syncthreads();
  if (q == 1) {
#pragma unroll
    for (int i = 0; i < 8; ++i) {
      *(float4*)&xs[(t0c + i) * STR + e0c]     = *(float4*)&acc[i][0];
      *(float4*)&xs[(t0c + i) * STR + e0c + 4] = *(float4*)&acc[i][4];
    }
  }
  __syncthreads();
  if (q == 0) {
#pragma unroll
    for (int i = 0; i < 8; ++i) {
      float4 a = *(const float4*)&xs[(t0c + i) * STR + e0c];
      float4 b = *(const float4*)&xs[(t0c + i) * STR + e0c + 4];
      acc[i][0] += a.x; acc[i][1] += a.y; acc[i][2] += a.z; acc[i][3] += a.w;
      acc[i][4] += b.x; acc[i][5] += b.y; acc[i][6] += b.z; acc[i][7] += b.w;
      *(float4*)&wsm[(t0c + i) * STR + e0c]     = *(float4*)&acc[i][0];
      *(float4*)&wsm[(t0c + i) * STR + e0c + 4] = *(float4*)&acc[i][4];
    }
    hist[l] = 0;
  }
  __syncthreads();

  // ---- epilogue (round-3 layout) ----
  float* logits  = wsm;   // [t][STR]
  float* scoresT = xs;    // [e][STR]
  const int t = l;

  float m = -__builtin_huge_valf();
#pragma unroll
  for (int e = 0; e < 16; ++e) m = fmaxf(m, logits[t * STR + q * 16 + e]);
  red[q * 64 + t] = m;
  __syncthreads();
  float gm = fmaxf(fmaxf(red[t], red[64 + t]), fmaxf(red[128 + t], red[192 + t]));
  if (q == 0) gmx[t] = gm;
  float z = 0.0f;
#pragma unroll
  for (int e = 0; e < 16; ++e) {
    float ev = expf(logits[t * STR + q * 16 + e] - gm);
    scoresT[(q * 16 + e) * STR + t] = ev;
    z += ev;
  }
  __syncthreads();
  red[q * 64 + t] = z;
  __syncthreads();
  float Z = red[t] + red[64 + t] + red[128 + t] + red[192 + t];
  float invZ = 1.0f / Z;
#pragma unroll
  for (int e = 0; e < 16; ++e) scoresT[(q * 16 + e) * STR + t] *= invZ;
  __syncthreads();

  // aux partials: sum scores over this block's tokens, per expert
  {
    const int e = l, g = q;
    float s = 0.0f;
#pragma unroll
    for (int tt = 0; tt < 16; ++tt) s += scoresT[e * STR + g * 16 + tt];
    red[g * 64 + e] = s;
  }
  __syncthreads();
  if (tid < 64) {
    float tot = red[tid] + red[64 + tid] + red[128 + tid] + red[192 + tid];
    atomicAdd(&gsum[bb * 64 + tid], tot);
  }

  // top-9 phase 1: per half (32 experts), strict > + ascending scan == jax tie-break
  if (tid < 128) {
    const int h = tid >> 6;
    const int eb = h * 32;
#pragma unroll 1
    for (int k = 0; k < 9; ++k) {
      float mv = -1.0f; int mi = eb;
#pragma unroll 4
      for (int e = 0; e < 32; ++e) {
        float v = scoresT[(eb + e) * STR + t];
        if (v > mv) { mv = v; mi = eb + e; }
      }
      cval[t * CSTR + h * 9 + k] = mv;
      cidx[t * CSTR + h * 9 + k] = mi;
      scoresT[mi * STR + t] = -1.0f;
    }
  }
  __syncthreads();

  // merge 18 -> top-9; flag near-ties for f64 refinement
  if (tid < 64) {
    float wv[9]; int wi[8];
#pragma unroll 1
    for (int k = 0; k < 9; ++k) {
      float mv = -1.0f; int mj = 0;
#pragma unroll 3
      for (int j = 0; j < 18; ++j) {
        float v = cval[t * CSTR + j];
        if (v > mv) { mv = v; mj = j; }
      }
      wv[k] = mv;
      if (k < 8) {
        wi[k] = cidx[t * CSTR + mj];
        atomicAdd(&hist[wi[k]], 1);
      }
      cval[t * CSTR + mj] = -1.0f;
    }
    bool flag = false;
#pragma unroll
    for (int k = 0; k < 8; ++k)
      if (wv[k + 1] >= wv[k] * (1.0f - 2.0e-5f)) flag = true;
    if (flag) {
      int p = atomicAdd(flag_cnt, 1);
      flag_tok[p] = tok_base + t;
    }
    // weights from f64 exp of logits (Z cancels in renorm; eps 1e-20 negligible)
    double ed[8]; double den = 0.0;
#pragma unroll
    for (int k = 0; k < 8; ++k) {
      ed[k] = exp((double)logits[t * STR + wi[k]] - (double)gmx[t]);
      den += ed[k];
    }
    const size_t tg = (size_t)(tok_base + t);
    *(float4*)(out + tg * 8) =
        make_float4((float)wi[0], (float)wi[1], (float)wi[2], (float)wi[3]);
    *(float4*)(out + tg * 8 + 4) =
        make_float4((float)wi[4], (float)wi[5], (float)wi[6], (float)wi[7]);
    *(float4*)(out + (size_t)TOKS * 8 + tg * 8) =
        make_float4((float)(ed[0] / den), (float)(ed[1] / den),
                    (float)(ed[2] / den), (float)(ed[3] / den));
    *(float4*)(out + (size_t)TOKS * 8 + tg * 8 + 4) =
        make_float4((float)(ed[4] / den), (float)(ed[5] / den),
                    (float)(ed[6] / den), (float)(ed[7] / den));
  }
  __syncthreads();
  if (tid < 64) atomicAdd(&gce[bb * 64 + tid], (float)hist[tid]);
}

// ---------------- f64 refinement for flagged (near-tie) tokens ----------------
__global__ __launch_bounds__(256) void moe_refine(
    const float* __restrict__ X, const float* __restrict__ W,
    float* __restrict__ out, float* __restrict__ gce,
    const int* __restrict__ flag_cnt, const int* __restrict__ flag_tok)
{
  __shared__ __align__(16) float xrow[DDIM];
  __shared__ double part[4][NEXP];
  const int tid = threadIdx.x;
  const int n = *flag_cnt;
  const int e = tid & 63;
  const int c = tid >> 6;          // K-chunk of 256
#pragma unroll 1
  for (int it = blockIdx.x; it < n; it += 256) {
    const int tok = flag_tok[it];
    __syncthreads();
    *(float4*)&xrow[tid * 4] = *(const float4*)&X[(size_t)tok * DDIM + tid * 4];
    __syncthreads();
    const float* wr = W + (size_t)e * DDIM + c * 256;
    const float* xr = xrow + c * 256;
    double s0 = 0.0, s1 = 0.0, s2 = 0.0, s3 = 0.0;
#pragma unroll 4
    for (int j = 0; j < 256; j += 4) {
      s0 += (double)xr[j]     * (double)wr[j];
      s1 += (double)xr[j + 1] * (double)wr[j + 1];
      s2 += (double)xr[j + 2] * (double)wr[j + 2];
      s3 += (double)xr[j + 3] * (double)wr[j + 3];
    }
    part[c][e] = (s0 + s1) + (s2 + s3);
    __syncthreads();
    if (tid < 64) {
      double cur = (part[0][e] + part[1][e]) + (part[2][e] + part[3][e]);
      int wi[8]; double wl[8];
#pragma unroll 1
      for (int k = 0; k < 8; ++k) {
        double mv = cur; int mi = e;
#pragma unroll
        for (int off = 1; off < 64; off <<= 1) {
          double ov = __shfl_xor(mv, off);
          int    oi = __shfl_xor(mi, off);
          if (ov > mv || (ov == mv && oi < mi)) { mv = ov; mi = oi; }
        }
        wi[k] = mi; wl[k] = mv;
        if (e == mi) cur = -1.0e300;   // knock out winner in its owner lane
      }
      if (e == 0) {
        int olde[8];
#pragma unroll
        for (int k = 0; k < 8; ++k) olde[k] = (int)out[(size_t)tok * 8 + k];
        double ex[8]; double den = 0.0;
#pragma unroll
        for (int k = 0; k < 8; ++k) { ex[k] = exp(wl[k] - wl[0]); den += ex[k]; }
#pragma unroll
        for (int k = 0; k < 8; ++k) {
          out[(size_t)tok * 8 + k] = (float)wi[k];
          out[(size_t)TOKS * 8 + (size_t)tok * 8 + k] = (float)(ex[k] / den);
        }
        const int bbb = tok >> 13;
#pragma unroll 1
        for (int k = 0; k < 8; ++k) {
          bool in_new = false, in_old = false;
          for (int j = 0; j < 8; ++j) {
            if (wi[j] == olde[k]) in_new = true;
            if (olde[j] == wi[k]) in_old = true;
          }
          if (!in_new) atomicAdd(&gce[bbb * 64 + olde[k]], -1.0f);
          if (!in_old) atomicAdd(&gce[bbb * 64 + wi[k]], 1.0f);
        }
      }
    }
  }
}

// ---------------- aux loss reduction ----------------
__global__ void moe_gate_aux(const float* __restrict__ gsum,
                             const float* __restrict__ gce,
                             float* __restrict__ out)
{
  __shared__ float r[256];
  const int tid = threadIdx.x;
  r[tid] = gce[tid] * gsum[tid];
  __syncthreads();
  for (int s = 128; s > 0; s >>= 1) {
    if (tid < s) r[tid] += r[tid + s];
    __syncthreads();
  }
  if (tid == 0)
    out[(size_t)TOKS * 16] = 0.1f * r[0] / ((float)SEQ * (float)NBATCH);
}

extern "C" void kernel_launch(void* const* d_in, const int* in_sizes, int n_in,
                              void* d_out, int out_size, void* d_ws, size_t ws_size,
                              hipStream_t stream)
{
  const float* X = (const float*)d_in[0];   // [4,8192,1024] fp32
  const float* W = (const float*)d_in[1];   // [64,1024] fp32
  float* out  = (float*)d_out;              // idx[T*8] | weights[T*8] | aux
  float* gsum = (float*)d_ws;               // [4][64]
  float* gce  = gsum + NBATCH * NEXP;       // [4][64]
  int* flag_cnt = (int*)((char*)d_ws + 2048);
  int* flag_tok = (int*)((char*)d_ws + 2176);

  hipMemsetAsync(d_ws, 0, 2176, stream);
  moe_gate_main<<<TOKS / TPB, 256, 0, stream>>>(X, W, out, gsum, gce, flag_cnt, flag_tok);
  moe_refine<<<256, 256, 0, stream>>>(X, W, out, gce, flag_cnt, flag_tok);
  moe_gate_aux<<<1, 256, 0, stream>>>(gsum, gce, out);
}